// Round 4
// baseline (242.504 us; speedup 1.0000x reference)
//
#include <hip/hip_runtime.h>

typedef __attribute__((ext_vector_type(8))) short short8;
typedef __attribute__((ext_vector_type(4))) short short4v;
typedef __attribute__((ext_vector_type(4))) float floatx4;

#define GLOBAL_AS __attribute__((address_space(1)))
#define LDS_AS __attribute__((address_space(3)))

__device__ __forceinline__ short f2bs(float f) {
    // RNE float -> bf16 (as short). Inputs finite here.
    union { float f; unsigned u; } v; v.f = f;
    unsigned r = v.u + 0x7fffu + ((v.u >> 16) & 1u);
    return (short)(r >> 16);
}

__device__ __forceinline__ short f2bs_fast(float f) {
    // round-half-up (non-negative finite inputs) - 2 VALU ops
    union { float f; unsigned u; } v; v.f = f;
    return (short)((v.u + 0x8000u) >> 16);
}

// ---------------- fused cast fp32 -> bf16 (x + Wq + Wk + Wv) ----------------
__global__ __launch_bounds__(256) void cast_all(const float* __restrict__ x,
                                                const float* __restrict__ Wq,
                                                const float* __restrict__ Wk,
                                                const float* __restrict__ Wv,
                                                short* __restrict__ xb,
                                                short* __restrict__ wb) {
    int b = blockIdx.x;
    int t = threadIdx.x;
    const float* src;
    short* dst;
    int idx;
    if (b < 8192) {
        src = x; dst = xb; idx = b * 1024 + t * 4;
    } else {
        int r = b - 8192;
        int wz = r >> 10;
        src = (wz == 0) ? Wq : (wz == 1) ? Wk : Wv;
        dst = wb + wz * (1 << 20);
        idx = (r & 1023) * 1024 + t * 4;
    }
    float4 v = *(const float4*)(src + idx);
    short4v o;
    o.x = f2bs(v.x); o.y = f2bs(v.y); o.z = f2bs(v.z); o.w = f2bs(v.w);
    *(short4v*)(dst + idx) = o;
}

// ---------------- QKV GEMM: P = xb @ W^T, BK=64 ----------------
// z=0 -> Q [b,h,n,d] pre-scaled by 0.125*log2(e); z=1 -> K [b,h,n,d]; z=2 -> V^T [b,h,d,n]
__global__ __launch_bounds__(256) void qkv_gemm(const short* __restrict__ xb,
                                                const short* __restrict__ wb,
                                                short* __restrict__ qout,
                                                short* __restrict__ kout,
                                                short* __restrict__ vtout) {
    __shared__ short As[128 * 64];  // [m][k], 16B chunks XOR-swizzled: slot = chunk ^ (row&7)
    __shared__ short Bs[128 * 64];
    const int K = 1024;
    int tid = threadIdx.x;
    int lane = tid & 63;
    int wid = tid >> 6;
    int quad = lane >> 4;
    int l16 = lane & 15;
    int wm = (wid >> 1) * 64;
    int wn = (wid & 1) * 64;
    int bm = blockIdx.x * 128;
    int bn = blockIdx.y * 128;
    const short* W = wb + (size_t)blockIdx.z * K * 1024;

    floatx4 acc[4][4];
#pragma unroll
    for (int i = 0; i < 4; i++)
#pragma unroll
        for (int j = 0; j < 4; j++) acc[i][j] = (floatx4){0.f, 0.f, 0.f, 0.f};

    int srow = tid >> 3;                             // 0..31 (base row of this thread's chunks)
    int ssw = ((tid & 7) ^ (srow & 7)) * 8;          // swizzled SOURCE element offset in 64-k row

    for (int kk = 0; kk < K; kk += 64) {
        __syncthreads();
#pragma unroll
        for (int l = 0; l < 4; l++) {
            const short* g = xb + (size_t)(bm + srow + l * 32) * K + kk + ssw;
            __builtin_amdgcn_global_load_lds((const GLOBAL_AS void*)g,
                                             (LDS_AS void*)(As + tid * 8 + l * 2048), 16, 0, 0);
        }
#pragma unroll
        for (int l = 0; l < 4; l++) {
            const short* g = W + (size_t)(bn + srow + l * 32) * K + kk + ssw;
            __builtin_amdgcn_global_load_lds((const GLOBAL_AS void*)g,
                                             (LDS_AS void*)(Bs + tid * 8 + l * 2048), 16, 0, 0);
        }
        __syncthreads();

#pragma unroll
        for (int s = 0; s < 2; s++) {
            int slot = ((s * 4 + quad) ^ (l16 & 7)) * 8;
            short8 af[4], bf[4];
#pragma unroll
            for (int i = 0; i < 4; i++)
                af[i] = *(const short8*)(As + (wm + i * 16 + l16) * 64 + slot);
#pragma unroll
            for (int j = 0; j < 4; j++)
                bf[j] = *(const short8*)(Bs + (wn + j * 16 + l16) * 64 + slot);
#pragma unroll
            for (int i = 0; i < 4; i++)
#pragma unroll
                for (int j = 0; j < 4; j++)
                    acc[i][j] = __builtin_amdgcn_mfma_f32_16x16x32_bf16(af[i], bf[j], acc[i][j], 0, 0, 0);
        }
    }

    // Epilogue. C/D layout: col = l16, row = quad*4 + r.
    if (blockIdx.z == 2) {
#pragma unroll
        for (int i = 0; i < 4; i++) {
#pragma unroll
            for (int j = 0; j < 4; j++) {
                int m = bm + wm + i * 16 + quad * 4;  // + r
                int c = bn + wn + j * 16 + l16;
                int b = m >> 11, nn = m & 2047, h = c >> 6, dd = c & 63;
                short4v pk;
                pk.x = f2bs(acc[i][j][0]);
                pk.y = f2bs(acc[i][j][1]);
                pk.z = f2bs(acc[i][j][2]);
                pk.w = f2bs(acc[i][j][3]);
                *(short4v*)(vtout + ((size_t)(b * 16 + h) * 64 + dd) * 2048 + nn) = pk;
            }
        }
    } else {
        short* dst = (blockIdx.z == 0) ? qout : kout;
        float qs = (blockIdx.z == 0) ? 0.180336881f : 1.0f;  // 0.125*log2(e) folded into Q
#pragma unroll
        for (int i = 0; i < 4; i++) {
#pragma unroll
            for (int j = 0; j < 4; j++) {
#pragma unroll
                for (int r = 0; r < 4; r++) {
                    int m = bm + wm + i * 16 + quad * 4 + r;
                    int c = bn + wn + j * 16 + l16;
                    dst[((size_t)((m >> 11) * 16 + (c >> 6)) * 2048 + (m & 2047)) * 64 + (c & 63)] =
                        f2bs(acc[i][j][r] * qs);
                }
            }
        }
    }
}

// ---------------- Flash attention (causal, no-max softmax, KV tile 128) ----------------
// q: pre-scaled bf16 [b,h,2048,64]; k: [b,h,2048,64]; vt: [b,h,64,2048]; out fp32 [b,2048,1024]
// Block = 256 thr (4 waves x 16 qrows = 64 q-rows). Q-tile pair (qx, 31-qx) -> 17 KV tiles.
// XCD-locality: flat grid, xcd = flat&7; all 16 q-blocks of a (b,h) land on one XCD so its
// K/V (512 KB) stays L2-resident; 8 heads per XCD = 4 MB = L2 size.
__global__ __launch_bounds__(256) void attn(const short* __restrict__ q,
                                            const short* __restrict__ k,
                                            const short* __restrict__ vt,
                                            float* __restrict__ out) {
    __shared__ short Ks[128 * 64];      // [key][d], slot = chunk ^ (key&7)
    __shared__ short Vs[64 * 128];      // [d][key], slot = (c&8)|((c^(d&7))&7)
    __shared__ short Ps[4 * 16 * 136];  // per-wave P [qrow][key], stride 136 (17 chunks)

    int tid = threadIdx.x;
    int lane = tid & 63;
    int wid = tid >> 6;
    int quad = lane >> 4;
    int l16 = lane & 15;

    int flat = blockIdx.x;
    int xcd = flat & 7;
    int slot = flat >> 3;           // 0..127
    int bh = xcd * 8 + (slot >> 4); // 8 (b,h) pairs per XCD
    int qx = slot & 15;
    int b = bh >> 4, h = bh & 15;

    const short* qp = q + (size_t)(b * 16 + h) * 2048 * 64;
    const short* kp = k + (size_t)(b * 16 + h) * 2048 * 64;
    const short* vp = vt + (size_t)(b * 16 + h) * 64 * 2048;

    // K staging: 128x64, 256 thr x 4 chunks. row = (tid>>3)+l*32, chunk = tid&7
    int krow = tid >> 3;
    int ksw = ((tid & 7) ^ (krow & 7)) * 8;
    // V staging: 64x128. d = (tid>>4)+l*16, chunk16 = tid&15
    int vd = tid >> 4;
    int vc = tid & 15;
    int vsw = ((vc & 8) | ((vc ^ vd) & 7)) * 8;

    short* pw = Ps + wid * (16 * 136);

    short8 ones;
#pragma unroll
    for (int i = 0; i < 8; i++) ones[i] = (short)0x3F80;  // bf16 1.0

    for (int phase = 0; phase < 2; phase++) {
        int qt = (phase == 0) ? qx : (31 - qx);
        int qbase = qt * 64;
        int qrow_w = qbase + wid * 16;  // wave owns rows qrow_w .. qrow_w+15

        short8 qf0 = *(const short8*)(qp + (size_t)(qrow_w + l16) * 64 + quad * 8);
        short8 qf1 = *(const short8*)(qp + (size_t)(qrow_w + l16) * 64 + 32 + quad * 8);

        floatx4 oacc[4];
#pragma unroll
        for (int d = 0; d < 4; d++) oacc[d] = (floatx4){0.f, 0.f, 0.f, 0.f};
        floatx4 lacc = (floatx4){0.f, 0.f, 0.f, 0.f};

        int ntiles = (qt >> 1) + 1;
        for (int t = 0; t < ntiles; t++) {
            int kvb = t * 128;
            __syncthreads();
#pragma unroll
            for (int l = 0; l < 4; l++) {
                const short* g = kp + (size_t)(kvb + krow + l * 32) * 64 + ksw;
                __builtin_amdgcn_global_load_lds((const GLOBAL_AS void*)g,
                                                 (LDS_AS void*)(Ks + tid * 8 + l * 2048), 16, 0, 0);
            }
#pragma unroll
            for (int l = 0; l < 4; l++) {
                const short* g = vp + (size_t)(vd + l * 16) * 2048 + kvb + vsw;
                __builtin_amdgcn_global_load_lds((const GLOBAL_AS void*)g,
                                                 (LDS_AS void*)(Vs + tid * 8 + l * 2048), 16, 0, 0);
            }
            __syncthreads();

            // ---- QK^T: S[16 x 128] per wave ----
            floatx4 sacc[8];
#pragma unroll
            for (int j = 0; j < 8; j++) sacc[j] = (floatx4){0.f, 0.f, 0.f, 0.f};
#pragma unroll
            for (int s = 0; s < 2; s++) {
#pragma unroll
                for (int j = 0; j < 8; j++) {
                    int row = j * 16 + l16;
                    short8 kf = *(const short8*)(Ks + row * 64 +
                                                 (((s * 4 + quad) ^ (row & 7)) * 8));
                    sacc[j] = __builtin_amdgcn_mfma_f32_16x16x32_bf16(
                        (s == 0) ? qf0 : qf1, kf, sacc[j], 0, 0, 0);
                }
            }

            // ---- exp2 + mask (diag tile only) + pack to P in LDS ----
            bool diag = (kvb + 127 > qrow_w);
#pragma unroll
            for (int r = 0; r < 4; r++) {
                int qr = qrow_w + quad * 4 + r;
#pragma unroll
                for (int j = 0; j < 8; j++) {
                    float p = __builtin_amdgcn_exp2f(sacc[j][r]);
                    if (diag) p = (kvb + j * 16 + l16 > qr) ? 0.f : p;
                    pw[(quad * 4 + r) * 136 + j * 16 + l16] = f2bs_fast(p);
                }
            }
            __threadfence_block();

            // ---- PV + row-sum via MFMA(P, ones) ----
#pragma unroll
            for (int s = 0; s < 4; s++) {
                short8 pf = *(const short8*)(pw + l16 * 136 + s * 32 + quad * 8);
                lacc = __builtin_amdgcn_mfma_f32_16x16x32_bf16(pf, ones, lacc, 0, 0, 0);
#pragma unroll
                for (int d = 0; d < 4; d++) {
                    int row = d * 16 + l16;
                    int c = s * 4 + quad;
                    int slotv = (c & 8) | ((c ^ (row & 7)) & 7);
                    short8 vf = *(const short8*)(Vs + row * 128 + slotv * 8);
                    oacc[d] = __builtin_amdgcn_mfma_f32_16x16x32_bf16(pf, vf, oacc[d], 0, 0, 0);
                }
            }
        }

        // lacc[r] = row sum replicated across all 16 cols (C-layout)
        float inv[4];
#pragma unroll
        for (int r = 0; r < 4; r++) inv[r] = 1.0f / lacc[r];

#pragma unroll
        for (int d = 0; d < 4; d++) {
#pragma unroll
            for (int r = 0; r < 4; r++) {
                int nn = qrow_w + quad * 4 + r;
                out[((size_t)b * 2048 + nn) * 1024 + h * 64 + d * 16 + l16] = oacc[d][r] * inv[r];
            }
        }
    }
}

extern "C" void kernel_launch(void* const* d_in, const int* in_sizes, int n_in,
                              void* d_out, int out_size, void* d_ws, size_t ws_size,
                              hipStream_t stream) {
    const float* x = (const float*)d_in[0];
    const float* Wq = (const float*)d_in[1];
    const float* Wk = (const float*)d_in[2];
    const float* Wv = (const float*)d_in[3];
    float* out = (float*)d_out;
    char* ws = (char*)d_ws;

    short* xb = (short*)ws;                          // 16 MB: [8192,1024] bf16
    short* wb = (short*)(ws + (16u << 20));          //  6 MB: [3,1024,1024] bf16
    short* qb = (short*)(ws + (22u << 20));          // 16 MB: [4,16,2048,64]
    short* kb = (short*)(ws + (38u << 20));          // 16 MB: [4,16,2048,64]
    short* vtb = (short*)(ws + (54u << 20));         // 16 MB: [4,16,64,2048]

    cast_all<<<8192 + 3 * 1024, 256, 0, stream>>>(x, Wq, Wk, Wv, xb, wb);
    qkv_gemm<<<dim3(64, 8, 3), 256, 0, stream>>>(xb, wb, qb, kb, vtb);
    attn<<<1024, 256, 0, stream>>>(qb, kb, vtb, out);
}

// Round 5
// 205.277 us; speedup vs baseline: 1.1813x; 1.1813x over previous
//
#include <hip/hip_runtime.h>

typedef __attribute__((ext_vector_type(8))) short short8;
typedef __attribute__((ext_vector_type(4))) short short4v;
typedef __attribute__((ext_vector_type(4))) float floatx4;
typedef __attribute__((ext_vector_type(16))) float floatx16;

#define GLOBAL_AS __attribute__((address_space(1)))
#define LDS_AS __attribute__((address_space(3)))

__device__ __forceinline__ short f2bs(float f) {
    // RNE float -> bf16 (as short). Inputs finite here.
    union { float f; unsigned u; } v; v.f = f;
    unsigned r = v.u + 0x7fffu + ((v.u >> 16) & 1u);
    return (short)(r >> 16);
}

#if __has_builtin(__builtin_amdgcn_cvt_pk_bf16_f32)
typedef __attribute__((ext_vector_type(2))) __bf16 bf16x2;
__device__ __forceinline__ unsigned pk2(float a, float b) {
    union { bf16x2 v; unsigned u; } u;
    u.v = __builtin_amdgcn_cvt_pk_bf16_f32(a, b);
    return u.u;
}
#else
__device__ __forceinline__ unsigned pk2(float a, float b) {
    // round-half-up, non-negative finite inputs
    union { float f; unsigned u; } x, y; x.f = a; y.f = b;
    return ((y.u + 0x8000u) & 0xffff0000u) | ((x.u + 0x8000u) >> 16);
}
#endif

// ---------------- fused cast fp32 -> bf16 (x + Wq + Wk + Wv) ----------------
__global__ __launch_bounds__(256) void cast_all(const float* __restrict__ x,
                                                const float* __restrict__ Wq,
                                                const float* __restrict__ Wk,
                                                const float* __restrict__ Wv,
                                                short* __restrict__ xb,
                                                short* __restrict__ wb) {
    int b = blockIdx.x;
    int t = threadIdx.x;
    const float* src;
    short* dst;
    int idx;
    if (b < 8192) {
        src = x; dst = xb; idx = b * 1024 + t * 4;
    } else {
        int r = b - 8192;
        int wz = r >> 10;
        src = (wz == 0) ? Wq : (wz == 1) ? Wk : Wv;
        dst = wb + wz * (1 << 20);
        idx = (r & 1023) * 1024 + t * 4;
    }
    float4 v = *(const float4*)(src + idx);
    short4v o;
    o.x = f2bs(v.x); o.y = f2bs(v.y); o.z = f2bs(v.z); o.w = f2bs(v.w);
    *(short4v*)(dst + idx) = o;
}

// ---------------- QKV GEMM: P = xb @ W^T, BK=64 (unchanged from R3) ----------------
__global__ __launch_bounds__(256) void qkv_gemm(const short* __restrict__ xb,
                                                const short* __restrict__ wb,
                                                short* __restrict__ qout,
                                                short* __restrict__ kout,
                                                short* __restrict__ vtout) {
    __shared__ short As[128 * 64];  // [m][k], 16B chunks XOR-swizzled: slot = chunk ^ (row&7)
    __shared__ short Bs[128 * 64];
    const int K = 1024;
    int tid = threadIdx.x;
    int lane = tid & 63;
    int wid = tid >> 6;
    int quad = lane >> 4;
    int l16 = lane & 15;
    int wm = (wid >> 1) * 64;
    int wn = (wid & 1) * 64;
    int bm = blockIdx.x * 128;
    int bn = blockIdx.y * 128;
    const short* W = wb + (size_t)blockIdx.z * K * 1024;

    floatx4 acc[4][4];
#pragma unroll
    for (int i = 0; i < 4; i++)
#pragma unroll
        for (int j = 0; j < 4; j++) acc[i][j] = (floatx4){0.f, 0.f, 0.f, 0.f};

    int srow = tid >> 3;
    int ssw = ((tid & 7) ^ (srow & 7)) * 8;

    for (int kk = 0; kk < K; kk += 64) {
        __syncthreads();
#pragma unroll
        for (int l = 0; l < 4; l++) {
            const short* g = xb + (size_t)(bm + srow + l * 32) * K + kk + ssw;
            __builtin_amdgcn_global_load_lds((const GLOBAL_AS void*)g,
                                             (LDS_AS void*)(As + tid * 8 + l * 2048), 16, 0, 0);
        }
#pragma unroll
        for (int l = 0; l < 4; l++) {
            const short* g = W + (size_t)(bn + srow + l * 32) * K + kk + ssw;
            __builtin_amdgcn_global_load_lds((const GLOBAL_AS void*)g,
                                             (LDS_AS void*)(Bs + tid * 8 + l * 2048), 16, 0, 0);
        }
        __syncthreads();

#pragma unroll
        for (int s = 0; s < 2; s++) {
            int slot = ((s * 4 + quad) ^ (l16 & 7)) * 8;
            short8 af[4], bf[4];
#pragma unroll
            for (int i = 0; i < 4; i++)
                af[i] = *(const short8*)(As + (wm + i * 16 + l16) * 64 + slot);
#pragma unroll
            for (int j = 0; j < 4; j++)
                bf[j] = *(const short8*)(Bs + (wn + j * 16 + l16) * 64 + slot);
#pragma unroll
            for (int i = 0; i < 4; i++)
#pragma unroll
                for (int j = 0; j < 4; j++)
                    acc[i][j] = __builtin_amdgcn_mfma_f32_16x16x32_bf16(af[i], bf[j], acc[i][j], 0, 0, 0);
        }
    }

    if (blockIdx.z == 2) {
#pragma unroll
        for (int i = 0; i < 4; i++) {
#pragma unroll
            for (int j = 0; j < 4; j++) {
                int m = bm + wm + i * 16 + quad * 4;
                int c = bn + wn + j * 16 + l16;
                int b = m >> 11, nn = m & 2047, h = c >> 6, dd = c & 63;
                short4v pk;
                pk.x = f2bs(acc[i][j][0]);
                pk.y = f2bs(acc[i][j][1]);
                pk.z = f2bs(acc[i][j][2]);
                pk.w = f2bs(acc[i][j][3]);
                *(short4v*)(vtout + ((size_t)(b * 16 + h) * 64 + dd) * 2048 + nn) = pk;
            }
        }
    } else {
        short* dst = (blockIdx.z == 0) ? qout : kout;
        float qs = (blockIdx.z == 0) ? 0.180336881f : 1.0f;  // 0.125*log2(e) folded into Q
#pragma unroll
        for (int i = 0; i < 4; i++) {
#pragma unroll
            for (int j = 0; j < 4; j++) {
#pragma unroll
                for (int r = 0; r < 4; r++) {
                    int m = bm + wm + i * 16 + quad * 4 + r;
                    int c = bn + wn + j * 16 + l16;
                    dst[((size_t)((m >> 11) * 16 + (c >> 6)) * 2048 + (m & 2047)) * 64 + (c & 63)] =
                        f2bs(acc[i][j][r] * qs);
                }
            }
        }
    }
}

// ---------------- Flash attention: 32x32x16 MFMA, S^T trick, Q128/KV128 ----------------
// q: pre-scaled bf16 [b,h,2048,64]; k: [b,h,2048,64]; vt: [b,h,64,2048]; out fp32 [b,2048,1024]
// Block = 256 thr (4 waves x 32 qrows = 128-row Q tile). Pair (qx,15-qx) -> 17 KV-128 tiles.
// 512 blocks, XCD-swizzled: 8 (b,h) per XCD (K+V = 4 MB = one L2); exactly 2 blocks/CU.
// S^T = K*Q^T so each lane owns ONE q-column: local row-sums, b64-packed P writes.
__global__ __launch_bounds__(256, 2) void attn(const short* __restrict__ q,
                                               const short* __restrict__ k,
                                               const short* __restrict__ vt,
                                               float* __restrict__ out) {
    __shared__ short Ks[128 * 64];      // [key][d], 16B slot = chunk ^ (key&7)
    __shared__ short Vs[64 * 128];      // [d][key], 16B slot = (c&8)|((c^(d&7))&7)
    __shared__ short Ps[4 * 32 * 136];  // per-wave P [qrow 0..31][key], stride 136 shorts

    int tid = threadIdx.x;
    int lane = tid & 63;
    int wid = tid >> 6;
    int l32 = lane & 31;
    int half = lane >> 5;   // 0/1

    int flat = blockIdx.x;
    int xcd = flat & 7;
    int slot = flat >> 3;            // 0..63
    int bh = xcd * 8 + (slot >> 3);  // 8 (b,h) per XCD
    int qx = slot & 7;
    int b = bh >> 4, h = bh & 15;

    const short* qp = q + (size_t)(b * 16 + h) * 2048 * 64;
    const short* kp = k + (size_t)(b * 16 + h) * 2048 * 64;
    const short* vp = vt + (size_t)(b * 16 + h) * 64 * 2048;

    // K staging: 128x64. row = (tid>>3)+l*32, chunk = tid&7 (swizzled at source)
    int krow = tid >> 3;
    int ksw = ((tid & 7) ^ (krow & 7)) * 8;
    // V staging: 64x128. d = (tid>>4)+l*16, chunk16 = tid&15
    int vd = tid >> 4;
    int vc = tid & 15;
    int vsw = ((vc & 8) | ((vc ^ vd) & 7)) * 8;

    short* pw = Ps + wid * (32 * 136);

    for (int phase = 0; phase < 2; phase++) {
        int qt = (phase == 0) ? qx : (15 - qx);
        int qbase = qt * 128;
        int qrow_w = qbase + wid * 32;      // wave owns q-rows qrow_w .. qrow_w+31
        int qlane = qrow_w + l32;           // this lane's q-row (S^T col)

        // Q fragments as B-operand: n = l32 (q-row), k = half*8 + j, 4 K-steps over d=64
        short8 qf[4];
#pragma unroll
        for (int s = 0; s < 4; s++)
            qf[s] = *(const short8*)(qp + (size_t)qlane * 64 + s * 16 + half * 8);

        floatx16 oacc[2];
#pragma unroll
        for (int nt = 0; nt < 2; nt++)
#pragma unroll
            for (int e = 0; e < 16; e++) oacc[nt][e] = 0.f;
        float rs = 0.f;

        int ntiles = qt + 1;
        for (int t = 0; t < ntiles; t++) {
            int kvb = t * 128;
            __syncthreads();
#pragma unroll
            for (int l = 0; l < 4; l++) {
                const short* g = kp + (size_t)(kvb + krow + l * 32) * 64 + ksw;
                __builtin_amdgcn_global_load_lds((const GLOBAL_AS void*)g,
                                                 (LDS_AS void*)(Ks + tid * 8 + l * 2048), 16, 0, 0);
            }
#pragma unroll
            for (int l = 0; l < 4; l++) {
                const short* g = vp + (size_t)(vd + l * 16) * 2048 + kvb + vsw;
                __builtin_amdgcn_global_load_lds((const GLOBAL_AS void*)g,
                                                 (LDS_AS void*)(Vs + tid * 8 + l * 2048), 16, 0, 0);
            }
            __syncthreads();

            // ---- S^T[key 0..127][q 0..31] = K * Q^T ----
            floatx16 sacc[4];
#pragma unroll
            for (int kb = 0; kb < 4; kb++)
#pragma unroll
                for (int e = 0; e < 16; e++) sacc[kb][e] = 0.f;
#pragma unroll
            for (int s = 0; s < 4; s++) {   // d-dim K-steps
#pragma unroll
                for (int kb = 0; kb < 4; kb++) {
                    int key = kb * 32 + l32;
                    int c = s * 2 + half;
                    short8 kf = *(const short8*)(Ks + key * 64 + ((c ^ (key & 7)) * 8));
                    sacc[kb] = __builtin_amdgcn_mfma_f32_32x32x16_bf16(kf, qf[s], sacc[kb], 0, 0, 0);
                }
            }

            // ---- exp2 + mask (diag tile only) + local row-sum + packed P write ----
            bool diag = (t == ntiles - 1) && (phase >= 0) && (kvb + 127 > qrow_w);
#pragma unroll
            for (int kb = 0; kb < 4; kb++) {
#pragma unroll
                for (int e = 0; e < 16; e++) {
                    float p = __builtin_amdgcn_exp2f(sacc[kb][e]);
                    if (diag) {
                        int key = kvb + kb * 32 + (e & 3) + 8 * (e >> 2) + 4 * half;
                        p = (key > qlane) ? 0.f : p;
                    }
                    sacc[kb][e] = p;
                    rs += p;
                }
                // C/D reg-quads hold 4 consecutive keys -> b64 writes
#pragma unroll
                for (int g = 0; g < 4; g++) {
                    int2 wv;
                    wv.x = pk2(sacc[kb][4 * g], sacc[kb][4 * g + 1]);
                    wv.y = pk2(sacc[kb][4 * g + 2], sacc[kb][4 * g + 3]);
                    *(int2*)(pw + l32 * 136 + kb * 32 + g * 8 + 4 * half) = wv;
                }
            }
            __threadfence_block();

            // ---- O += P * V : A = P[q][key], B = V^T[d][key] ----
#pragma unroll
            for (int s = 0; s < 8; s++) {   // key K-steps of 16
                short8 pf = *(const short8*)(pw + l32 * 136 + s * 16 + half * 8);
#pragma unroll
                for (int nt = 0; nt < 2; nt++) {
                    int d = nt * 32 + l32;
                    int c = s * 2 + half;
                    int sl = (c & 8) | ((c ^ (d & 7)) & 7);
                    short8 vf = *(const short8*)(Vs + d * 128 + sl * 8);
                    oacc[nt] = __builtin_amdgcn_mfma_f32_32x32x16_bf16(pf, vf, oacc[nt], 0, 0, 0);
                }
            }
        }

        // ---- epilogue: rows of O live across lanes; fetch 1/l via shuffle ----
        float tot = rs + __shfl_xor(rs, 32);
        float inv = 1.0f / tot;
        float invr[16];
#pragma unroll
        for (int e = 0; e < 16; e++)
            invr[e] = __shfl(inv, (e & 3) + 8 * (e >> 2) + 4 * half);
#pragma unroll
        for (int nt = 0; nt < 2; nt++) {
#pragma unroll
            for (int e = 0; e < 16; e++) {
                int r = (e & 3) + 8 * (e >> 2) + 4 * half;
                int nn = qrow_w + r;
                out[((size_t)b * 2048 + nn) * 1024 + h * 64 + nt * 32 + l32] = oacc[nt][e] * invr[e];
            }
        }
    }
}

extern "C" void kernel_launch(void* const* d_in, const int* in_sizes, int n_in,
                              void* d_out, int out_size, void* d_ws, size_t ws_size,
                              hipStream_t stream) {
    const float* x = (const float*)d_in[0];
    const float* Wq = (const float*)d_in[1];
    const float* Wk = (const float*)d_in[2];
    const float* Wv = (const float*)d_in[3];
    float* out = (float*)d_out;
    char* ws = (char*)d_ws;

    short* xb = (short*)ws;                          // 16 MB: [8192,1024] bf16
    short* wb = (short*)(ws + (16u << 20));          //  6 MB: [3,1024,1024] bf16
    short* qb = (short*)(ws + (22u << 20));          // 16 MB: [4,16,2048,64]
    short* kb = (short*)(ws + (38u << 20));          // 16 MB: [4,16,2048,64]
    short* vtb = (short*)(ws + (54u << 20));         // 16 MB: [4,16,64,2048]

    cast_all<<<8192 + 3 * 1024, 256, 0, stream>>>(x, Wq, Wk, Wv, xb, wb);
    qkv_gemm<<<dim3(64, 8, 3), 256, 0, stream>>>(xb, wb, qb, kb, vtb);
    attn<<<512, 256, 0, stream>>>(qb, kb, vtb, out);
}